// Round 8
// baseline (125.576 us; speedup 1.0000x reference)
//
#include <hip/hip_runtime.h>
#include <hip/hip_bf16.h>

// STDP via the antisymmetric-kernel identity (verified R6, absmax 9.8e-4):
//   out[q,p] = 4w(1-w) * A_SCALE * sum_{b,t} post_s[b,t,q] * Z[b,t,p]
//   Z = pre_tr - pre_rt;  tr = causal decay scan, rt = anti-causal scan
//   (rt[t] = decay*rt[t+1] + s[t] for t>=1, rt[0]=0).  K = B*T = 2048.
//   AT[q][b*128+t] = post_spikes (bf16);  BT[p][b*128+t] = Z (bf16, one round)

typedef __attribute__((ext_vector_type(8))) short bf16x8;
typedef __attribute__((ext_vector_type(4))) float f32x4;

#define GN 2048
#define KTOT 2048
#define A_SCALE (0.01f / 16.0f)
#define FST 68   // fbuf dword stride (16B-aligned float4 rows)
#define ZST 66   // zbuf elem stride (8B-aligned packed writes)

#define GLOAD_LDS16(gp, lp) \
    __builtin_amdgcn_global_load_lds((const __attribute__((address_space(1))) void*)(gp), \
                                     (__attribute__((address_space(3))) void*)(lp), 16, 0, 0)

__device__ __forceinline__ unsigned bf16bits(float x) {
    __hip_bfloat16 h = __float2bfloat16(x);
    return (unsigned)*(unsigned short*)&h;
}

// ---------------------------------------------------------------------------
// Kernel 1: transpose (+ double scan for the pre side), float4 global loads.
// grid (32, 16, 2), block 256 (4 waves). z=0: post -> AT (spikes only),
// z=1: pre -> BT (Z = tr - rt, fp32 scans).
// zbuf OVERLAYS fbuf (sync between last fbuf read and first zbuf write):
// LDS 34816 B -> 4 blocks/CU (was 51.7 KB / 3 blocks).
// ---------------------------------------------------------------------------
__global__ __launch_bounds__(256, 4) void trace_kernel(
    const float* __restrict__ pre,
    const float* __restrict__ post,
    const int* __restrict__ dtp,
    __hip_bfloat16* __restrict__ AT,
    __hip_bfloat16* __restrict__ BT)
{
    __shared__ float fbuf[128 * FST];                    // 34816 B, t-major fp32
    __hip_bfloat16* zbuf = (__hip_bfloat16*)fbuf;        // overlay, t-major bf16

    const int tid = threadIdx.x;
    const int w   = tid >> 6;    // wave 0..3
    const int l   = tid & 63;
    const int nq  = tid & 15;    // float4 group along n
    const int tl  = tid >> 4;    // t-row within a 16-row pass
    const int n0  = blockIdx.x * 64;
    const int b   = blockIdx.y;
    const int a   = blockIdx.z;  // 0: post->AT, 1: pre->BT

    int di = dtp[0];
    float dtf = (di > 0 && di < 1000000) ? (float)di : *(const float*)dtp;
    const float decay = __expf(-dtf / 20.0f);

    if (a == 0) {
        // spikes only: float4 load -> packed bf16x4 store (fbuf never used)
        #pragma unroll
        for (int pass = 0; pass < 8; ++pass) {
            const int t = pass * 16 + tl;
            float4 v = *(const float4*)&post[((size_t)b * 128 + t) * GN + n0 + 4 * nq];
            uint2 pk;
            pk.x = bf16bits(v.x) | (bf16bits(v.y) << 16);
            pk.y = bf16bits(v.z) | (bf16bits(v.w) << 16);
            *(uint2*)&zbuf[t * ZST + 4 * nq] = pk;
        }
        __syncthreads();
    } else {
        #pragma unroll
        for (int pass = 0; pass < 8; ++pass) {
            const int t = pass * 16 + tl;
            float4 v = *(const float4*)&pre[((size_t)b * 128 + t) * GN + n0 + 4 * nq];
            *(float4*)&fbuf[t * FST + 4 * nq] = v;
        }
        __syncthreads();

        const int t0 = 32 * w;   // this wave's t segment [t0, t0+32)
        // forward scan: tr[t] = decay*tr[t-1] + s[t] (t>=1), tr[0]=0
        float carry = 0.0f;
        #pragma unroll 8
        for (int t = 1; t < t0; ++t)
            carry = decay * carry + fbuf[t * FST + l];
        float z[32];
        #pragma unroll
        for (int j = 0; j < 32; ++j) {
            const int t = t0 + j;
            if (t >= 1) carry = decay * carry + fbuf[t * FST + l];
            z[j] = carry;                     // tr (t=0 -> 0)
        }
        // backward scan: rt[t] = decay*rt[t+1] + s[t]; subtract for t>=1
        float bc = 0.0f;
        #pragma unroll 8
        for (int t = 127; t >= t0 + 32; --t)
            bc = decay * bc + fbuf[t * FST + l];
        #pragma unroll
        for (int j = 31; j >= 0; --j) {
            const int t = t0 + j;
            bc = decay * bc + fbuf[t * FST + l];
            if (t >= 1) z[j] -= bc;           // Z = tr - rt   (Z[0] = 0)
        }
        __syncthreads();   // ALL waves done reading fbuf before zbuf overlay
        #pragma unroll
        for (int j = 0; j < 32; ++j)
            zbuf[(t0 + j) * ZST + l] = __float2bfloat16(z[j]);
        __syncthreads();
    }

    // transpose-write: 1024 16B-chunks/block, 4 per thread, coalesced.
    __hip_bfloat16* dst = (a == 0) ? AT : BT;
    #pragma unroll
    for (int j = 0; j < 4; ++j) {
        const int c  = tid + 256 * j;   // 0..1023
        const int n  = c >> 4;          // 0..63
        const int tc = c & 15;          // 8-t chunk
        unsigned int vv[8];
        #pragma unroll
        for (int i = 0; i < 8; ++i)
            vv[i] = *(const unsigned short*)&zbuf[(8 * tc + i) * ZST + n];
        uint4 pk;
        pk.x = vv[0] | (vv[1] << 16);
        pk.y = vv[2] | (vv[3] << 16);
        pk.z = vv[4] | (vv[5] << 16);
        pk.w = vv[6] | (vv[7] << 16);
        *(uint4*)(dst + (size_t)(n0 + n) * KTOT + b * 128 + tc * 8) = pk;
    }
}

// ---------------------------------------------------------------------------
// Kernel 2: out = 4w(1-w)*A_SCALE * (AT * BT^T), full K=2048, fused epilogue.
// 128x64 tile -> grid (32,16) = 512 blocks = 2 blocks/CU.  LDS-traffic math:
// wave=64x32 reads (128+64) B per unit-K; 2048 waves x 2048 K = 805 MB LDS
// reads (~10.2 us) + 5.1 us staging = ~15.3 us pipe floor, vs 20.5 us for the
// R7 64x64 tile.  2 resident blocks: one block's compute phase (~650 cyc of
// ds_read+MFMA) covers the other's barrier drain.  BK=64, single-buffer
// global_load_lds, XOR k-chunk source swizzle.  acc[4][2], VGPR ~52,
// LDS 24 KB.  No split-K, no combine.
// ---------------------------------------------------------------------------
__global__ __launch_bounds__(256) void stdp_gemm(
    const __hip_bfloat16* __restrict__ AT,
    const __hip_bfloat16* __restrict__ BT,
    const float* __restrict__ W,
    float* __restrict__ out)
{
    __shared__ alignas(16) __hip_bfloat16 As[128 * 64];
    __shared__ alignas(16) __hip_bfloat16 Bs[64 * 64];

    const int tid  = threadIdx.x;
    const int lane = tid & 63;
    const int wv   = tid >> 6;          // wave 0..3
    const int wm   = (wv >> 1) * 64;    // {0,64}
    const int wn   = (wv & 1) * 32;     // {0,32}
    const int RM   = blockIdx.y * 128;  // q base
    const int CN   = blockIdx.x * 64;   // p base
    const int l15  = lane & 15;
    const int quad = lane >> 4;

    f32x4 acc[4][2] = {};

    for (int k0 = 0; k0 < KTOT; k0 += 64) {
        __syncthreads();  // previous iter's ds_reads done before overwrite
        #pragma unroll
        for (int it = 0; it < 4; ++it) {
            const int cbase = it * 256 + wv * 64;      // wave-uniform chunk base
            const int c     = cbase + lane;            // 16B chunk id 0..1023
            const int row   = c >> 3;                  // 0..127
            const int kc    = (c & 7) ^ (row & 7);     // XOR swizzle (self-inverse)
            GLOAD_LDS16(AT + (size_t)(RM + row) * KTOT + k0 + kc * 8, As + (size_t)cbase * 8);
        }
        #pragma unroll
        for (int it = 0; it < 2; ++it) {
            const int cbase = it * 256 + wv * 64;
            const int c     = cbase + lane;            // 0..511
            const int row   = c >> 3;                  // 0..63
            const int kc    = (c & 7) ^ (row & 7);
            GLOAD_LDS16(BT + (size_t)(CN + row) * KTOT + k0 + kc * 8, Bs + (size_t)cbase * 8);
        }
        __syncthreads();  // vmcnt(0) drain: staged data visible

        #pragma unroll
        for (int kk = 0; kk < 64; kk += 32) {
            const int jg = (kk >> 3) + quad;           // k-chunk 0..3 / 4..7
            bf16x8 af[4], bfr[2];
            #pragma unroll
            for (int i = 0; i < 4; ++i) {
                const int mr = wm + i * 16 + l15;
                af[i] = *(const bf16x8*)(As + mr * 64 + ((jg ^ (mr & 7)) * 8));
            }
            #pragma unroll
            for (int j = 0; j < 2; ++j) {
                const int nr = wn + j * 16 + l15;
                bfr[j] = *(const bf16x8*)(Bs + nr * 64 + ((jg ^ (nr & 7)) * 8));
            }
            #pragma unroll
            for (int i = 0; i < 4; ++i)
                #pragma unroll
                for (int j = 0; j < 2; ++j)
                    acc[i][j] = __builtin_amdgcn_mfma_f32_16x16x32_bf16(
                        af[i], bfr[j], acc[i][j], 0, 0, 0);
        }
    }

    // fused epilogue: C/D layout col = lane&15, row = quad*4 + reg (m89)
    #pragma unroll
    for (int i = 0; i < 4; ++i) {
        #pragma unroll
        for (int r = 0; r < 4; ++r) {
            const int q = RM + wm + i * 16 + quad * 4 + r;
            #pragma unroll
            for (int j = 0; j < 2; ++j) {
                const int p = CN + wn + j * 16 + l15;
                const float w  = W[(size_t)q * GN + p];
                const float wf = 4.0f * w * (1.0f - w);
                out[(size_t)q * GN + p] = wf * A_SCALE * acc[i][j][r];
            }
        }
    }
}

extern "C" void kernel_launch(void* const* d_in, const int* in_sizes, int n_in,
                              void* d_out, int out_size, void* d_ws, size_t ws_size,
                              hipStream_t stream) {
    const float* W    = (const float*)d_in[0];  // [2048][2048]
    const float* pre  = (const float*)d_in[1];  // [16][128][2048]
    const float* post = (const float*)d_in[2];  // [16][128][2048]
    const int*   dt   = (const int*)d_in[3];
    float* out = (float*)d_out;

    __hip_bfloat16* AT = (__hip_bfloat16*)d_ws;            // 8 MB
    __hip_bfloat16* BT = AT + (size_t)GN * KTOT;           // +8 MB

    trace_kernel<<<dim3(32, 16, 2), 256, 0, stream>>>(pre, post, dt, AT, BT);
    stdp_gemm<<<dim3(32, 16), 256, 0, stream>>>(AT, BT, W, out);
}

// Round 9
// 122.751 us; speedup vs baseline: 1.0230x; 1.0230x over previous
//
#include <hip/hip_runtime.h>
#include <hip/hip_bf16.h>

// STDP via the antisymmetric-kernel identity (verified R6, absmax 9.8e-4):
//   out[q,p] = 4w(1-w) * A_SCALE * sum_{b,t} post_s[b,t,q] * Z[b,t,p]
//   Z = pre_tr - pre_rt;  tr = causal decay scan, rt = anti-causal scan
//   (rt[t] = decay*rt[t+1] + s[t] for t>=1, rt[0]=0).  K = B*T = 2048.
//   AT[q][b*128+t] = post_spikes (bf16);  BT[p][b*128+t] = Z (bf16, one round)

typedef __attribute__((ext_vector_type(8))) short bf16x8;
typedef __attribute__((ext_vector_type(4))) float f32x4;

#define GN 2048
#define KTOT 2048
#define A_SCALE (0.01f / 16.0f)
#define FST 68   // fbuf dword stride (16B-aligned float4 rows)
#define ZST 66   // zbuf elem stride (8B-aligned packed writes)

#define GLOAD_LDS16(gp, lp) \
    __builtin_amdgcn_global_load_lds((const __attribute__((address_space(1))) void*)(gp), \
                                     (__attribute__((address_space(3))) void*)(lp), 16, 0, 0)

__device__ __forceinline__ unsigned bf16bits(float x) {
    __hip_bfloat16 h = __float2bfloat16(x);
    return (unsigned)*(unsigned short*)&h;
}

// ---------------------------------------------------------------------------
// Kernel 1: transpose (+ double scan for the pre side), float4 global loads.
// grid (32, 16, 2), block 256 (4 waves). z=0: post -> AT (spikes only),
// z=1: pre -> BT (Z = tr - rt, fp32 scans).  zbuf overlays fbuf.
// LDS 34816 B -> 4 blocks/CU.  (R8-measured ~11.6 us)
// ---------------------------------------------------------------------------
__global__ __launch_bounds__(256, 4) void trace_kernel(
    const float* __restrict__ pre,
    const float* __restrict__ post,
    const int* __restrict__ dtp,
    __hip_bfloat16* __restrict__ AT,
    __hip_bfloat16* __restrict__ BT)
{
    __shared__ float fbuf[128 * FST];                    // 34816 B, t-major fp32
    __hip_bfloat16* zbuf = (__hip_bfloat16*)fbuf;        // overlay, t-major bf16

    const int tid = threadIdx.x;
    const int w   = tid >> 6;    // wave 0..3
    const int l   = tid & 63;
    const int nq  = tid & 15;    // float4 group along n
    const int tl  = tid >> 4;    // t-row within a 16-row pass
    const int n0  = blockIdx.x * 64;
    const int b   = blockIdx.y;
    const int a   = blockIdx.z;  // 0: post->AT, 1: pre->BT

    int di = dtp[0];
    float dtf = (di > 0 && di < 1000000) ? (float)di : *(const float*)dtp;
    const float decay = __expf(-dtf / 20.0f);

    if (a == 0) {
        #pragma unroll
        for (int pass = 0; pass < 8; ++pass) {
            const int t = pass * 16 + tl;
            float4 v = *(const float4*)&post[((size_t)b * 128 + t) * GN + n0 + 4 * nq];
            uint2 pk;
            pk.x = bf16bits(v.x) | (bf16bits(v.y) << 16);
            pk.y = bf16bits(v.z) | (bf16bits(v.w) << 16);
            *(uint2*)&zbuf[t * ZST + 4 * nq] = pk;
        }
        __syncthreads();
    } else {
        #pragma unroll
        for (int pass = 0; pass < 8; ++pass) {
            const int t = pass * 16 + tl;
            float4 v = *(const float4*)&pre[((size_t)b * 128 + t) * GN + n0 + 4 * nq];
            *(float4*)&fbuf[t * FST + 4 * nq] = v;
        }
        __syncthreads();

        const int t0 = 32 * w;   // this wave's t segment [t0, t0+32)
        float carry = 0.0f;
        #pragma unroll 8
        for (int t = 1; t < t0; ++t)
            carry = decay * carry + fbuf[t * FST + l];
        float z[32];
        #pragma unroll
        for (int j = 0; j < 32; ++j) {
            const int t = t0 + j;
            if (t >= 1) carry = decay * carry + fbuf[t * FST + l];
            z[j] = carry;                     // tr (t=0 -> 0)
        }
        float bc = 0.0f;
        #pragma unroll 8
        for (int t = 127; t >= t0 + 32; --t)
            bc = decay * bc + fbuf[t * FST + l];
        #pragma unroll
        for (int j = 31; j >= 0; --j) {
            const int t = t0 + j;
            bc = decay * bc + fbuf[t * FST + l];
            if (t >= 1) z[j] -= bc;           // Z = tr - rt   (Z[0] = 0)
        }
        __syncthreads();   // all waves done reading fbuf before zbuf overlay
        #pragma unroll
        for (int j = 0; j < 32; ++j)
            zbuf[(t0 + j) * ZST + l] = __float2bfloat16(z[j]);
        __syncthreads();
    }

    __hip_bfloat16* dst = (a == 0) ? AT : BT;
    #pragma unroll
    for (int j = 0; j < 4; ++j) {
        const int c  = tid + 256 * j;   // 0..1023
        const int n  = c >> 4;          // 0..63
        const int tc = c & 15;          // 8-t chunk
        unsigned int vv[8];
        #pragma unroll
        for (int i = 0; i < 8; ++i)
            vv[i] = *(const unsigned short*)&zbuf[(8 * tc + i) * ZST + n];
        uint4 pk;
        pk.x = vv[0] | (vv[1] << 16);
        pk.y = vv[2] | (vv[3] << 16);
        pk.z = vv[4] | (vv[5] << 16);
        pk.w = vv[6] | (vv[7] << 16);
        *(uint4*)(dst + (size_t)(n0 + n) * KTOT + b * 128 + tc * 8) = pk;
    }
}

// ---------------------------------------------------------------------------
// Kernel 2: out = 4w(1-w)*A_SCALE * (AT * BT^T), full K=2048, fused epilogue.
// 64x64 tile, grid (32,32) = 1024 blocks = 4 blocks/CU (R5/R7-proven m114
// overlap regime) with BK=128: 16 K-iterations instead of 32 -> HALF the
// __syncthreads+vmcnt(0) drains (R8 post-mortem: drain, not LDS bytes, is
// the limiter), 16 ds_read_b128 + 16 MFMA per barrier to amortize.
// LDS 2 x 16 KB = 32 KB -> 4 blocks/CU still fits (128 <= 160 KB).
// 16-slot XOR swizzle (slot = kc ^ (row&15)) on the source pointer; fragment
// reads spread slots over 8 bank-quads -> 2-way = free.  VGPR ~60.
// ---------------------------------------------------------------------------
__global__ __launch_bounds__(256) void stdp_gemm(
    const __hip_bfloat16* __restrict__ AT,
    const __hip_bfloat16* __restrict__ BT,
    const float* __restrict__ W,
    float* __restrict__ out)
{
    __shared__ alignas(16) __hip_bfloat16 As[64 * 128];
    __shared__ alignas(16) __hip_bfloat16 Bs[64 * 128];

    const int tid  = threadIdx.x;
    const int lane = tid & 63;
    const int wv   = tid >> 6;          // wave 0..3
    const int wm   = (wv >> 1) * 32;    // {0,32}
    const int wn   = (wv & 1) * 32;     // {0,32}
    const int RM   = blockIdx.y * 64;   // q base
    const int CN   = blockIdx.x * 64;   // p base
    const int l15  = lane & 15;
    const int quad = lane >> 4;

    f32x4 acc[2][2] = {};

    for (int k0 = 0; k0 < KTOT; k0 += 128) {
        __syncthreads();  // previous iter's ds_reads done before overwrite
        // stage A and B: each 64 rows x 16 chunks (16B) = 1024 chunks
        #pragma unroll
        for (int it = 0; it < 4; ++it) {
            const int cbase = it * 256 + wv * 64;      // wave-uniform chunk base
            const int c     = cbase + lane;            // 0..1023
            const int row   = c >> 4;                  // 0..63
            const int kc    = (c & 15) ^ (row & 15);   // XOR swizzle (self-inverse)
            GLOAD_LDS16(AT + (size_t)(RM + row) * KTOT + k0 + kc * 8, As + (size_t)cbase * 8);
            GLOAD_LDS16(BT + (size_t)(CN + row) * KTOT + k0 + kc * 8, Bs + (size_t)cbase * 8);
        }
        __syncthreads();  // vmcnt(0) drain: staged data visible

        #pragma unroll
        for (int kk = 0; kk < 128; kk += 32) {
            const int jg = (kk >> 3) + quad;           // k-chunk 0..15
            bf16x8 af[2], bfr[2];
            #pragma unroll
            for (int i = 0; i < 2; ++i) {
                const int mr = wm + i * 16 + l15;
                af[i] = *(const bf16x8*)(As + mr * 128 + ((jg ^ (mr & 15)) * 8));
                const int nr = wn + i * 16 + l15;
                bfr[i] = *(const bf16x8*)(Bs + nr * 128 + ((jg ^ (nr & 15)) * 8));
            }
            #pragma unroll
            for (int i = 0; i < 2; ++i)
                #pragma unroll
                for (int j = 0; j < 2; ++j)
                    acc[i][j] = __builtin_amdgcn_mfma_f32_16x16x32_bf16(
                        af[i], bfr[j], acc[i][j], 0, 0, 0);
        }
    }

    // fused epilogue: C/D layout col = lane&15, row = quad*4 + reg (m89)
    #pragma unroll
    for (int i = 0; i < 2; ++i) {
        #pragma unroll
        for (int r = 0; r < 4; ++r) {
            const int q = RM + wm + i * 16 + quad * 4 + r;
            #pragma unroll
            for (int j = 0; j < 2; ++j) {
                const int p = CN + wn + j * 16 + l15;
                const float w  = W[(size_t)q * GN + p];
                const float wf = 4.0f * w * (1.0f - w);
                out[(size_t)q * GN + p] = wf * A_SCALE * acc[i][j][r];
            }
        }
    }
}

extern "C" void kernel_launch(void* const* d_in, const int* in_sizes, int n_in,
                              void* d_out, int out_size, void* d_ws, size_t ws_size,
                              hipStream_t stream) {
    const float* W    = (const float*)d_in[0];  // [2048][2048]
    const float* pre  = (const float*)d_in[1];  // [16][128][2048]
    const float* post = (const float*)d_in[2];  // [16][128][2048]
    const int*   dt   = (const int*)d_in[3];
    float* out = (float*)d_out;

    __hip_bfloat16* AT = (__hip_bfloat16*)d_ws;            // 8 MB
    __hip_bfloat16* BT = AT + (size_t)GN * KTOT;           // +8 MB

    trace_kernel<<<dim3(32, 16, 2), 256, 0, stream>>>(pre, post, dt, AT, BT);
    stdp_gemm<<<dim3(32, 32), 256, 0, stream>>>(AT, BT, W, out);
}